// Round 3
// baseline (1377.024 us; speedup 1.0000x reference)
//
#include <hip/hip_runtime.h>
#include <hip/hip_bf16.h>
#include <string.h>

#define NPT   16384
#define NBAT  16
#define CH    288
#define SP    256
#define KS    16
#define OFF_FEAT 12288L
#define OFF_IND  1191936L

#define R16(M) M(0) M(1) M(2) M(3) M(4) M(5) M(6) M(7) M(8) M(9) M(10) M(11) M(12) M(13) M(14) M(15)

// ---------- helpers ----------
__device__ __forceinline__ float bfbits(unsigned short u){
  unsigned int x = ((unsigned int)u) << 16; float f; __builtin_memcpy(&f,&x,4); return f;
}
__device__ __forceinline__ float ldf(const void* p, long i, int isb){
  if (isb) return __bfloat162float(((const __hip_bfloat16*)p)[i]);
  return ((const float*)p)[i];
}
__device__ __forceinline__ void sto(void* p, long i, float v, int isb){
  if (isb) ((__hip_bfloat16*)p)[i] = __float2bfloat16(v);
  else     ((float*)p)[i] = v;
}
__device__ __forceinline__ void gload_lds(const void* g, void* l){
  __builtin_amdgcn_global_load_lds((const __attribute__((address_space(1))) void*)g,
      (__attribute__((address_space(3))) void*)l, 16, 0, 0);
}

typedef __attribute__((ext_vector_type(8))) short bf16x8;
typedef __attribute__((ext_vector_type(4))) float f32x4;

// ---------- 0. input dtype detection ----------
__global__ void detect_k(const void* __restrict__ xyz, int* __restrict__ flag){
  __shared__ float red[256];
  const int t = threadIdx.x;
  const unsigned short* u = (const unsigned short*)xyz;
  float m = 0.f;
  for (int i = t; i < 4096; i += 256){
    float f = fabsf(bfbits(u[i]));
    if (f != f) f = 1e30f;
    m = fmaxf(m, f);
  }
  red[t] = m; __syncthreads();
  for (int s = 128; s; s >>= 1){ if (t < s) red[t] = fmaxf(red[t], red[t+s]); __syncthreads(); }
  if (t == 0) *flag = (red[0] < 2.0f) ? 1 : 0;
}

// ---------- 0b. xyz -> f32 SoA ----------
__global__ __launch_bounds__(256) void cvtxyz_k(const void* __restrict__ xyz,
    const int* __restrict__ flag, float* __restrict__ X, float* __restrict__ Y,
    float* __restrict__ Z){
  const int e = blockIdx.x*256 + threadIdx.x;       // < 786432
  const int isb = *flag;
  float v = ldf(xyz, e, isb);
  int b = e / (NPT*3), r = e - b*(NPT*3), i = r/3, c = r - i*3;
  float* P = (c==0) ? X : ((c==1) ? Y : Z);
  P[b*NPT + i] = v;
}

// ---------- 0c. W -> bf16 [288][296] + BN scale/shift ----------
__global__ __launch_bounds__(256) void cvtw_k(const void* __restrict__ W,
    const void* __restrict__ g, const void* __restrict__ bb,
    const void* __restrict__ m, const void* __restrict__ v,
    const int* __restrict__ flag, __hip_bfloat16* __restrict__ Wbf,
    float* __restrict__ scale, float* __restrict__ shift, int Kin){
  const int isb = *flag;
  const int idx = blockIdx.x*256 + threadIdx.x;
  if (idx < 288*296){
    int o = idx / 296, k = idx - o*296;
    float val = (k < Kin) ? ldf(W, (long)o*Kin + k, isb) : 0.f;
    Wbf[idx] = __float2bfloat16(val);
  }
  if (idx < 288){
    float sc = ldf(g, idx, isb) * rsqrtf(ldf(v, idx, isb) + 1e-5f);
    scale[idx] = sc;
    shift[idx] = ldf(bb, idx, isb) - ldf(m, idx, isb)*sc;
  }
}

// ---------- 1. FPS ----------
// 1024 threads x 16 points held in EXPLICIT SCALAR registers (macro-expanded,
// pure SSA -- round-2 arrays were never promoted: VGPR=84 proved scratch
// residency, 2.7us/iter of L1 traffic). Exact numpy semantics: contract off,
// (dx^2+dy^2)+dz^2, strict > with ascending index, min-index tie-break.
__global__ __launch_bounds__(1024, 4) void fps_k(const float* __restrict__ X,
    const float* __restrict__ Y, const float* __restrict__ Z,
    const int* __restrict__ flag, float* __restrict__ nxyz, void* __restrict__ dout){
  #pragma clang fp contract(off)
  const int b = blockIdx.x, t = threadIdx.x;
  const int isb = *flag;
  const int base = b*NPT;
#define DECLP(i) float px##i, py##i, pz##i, dd##i;
  R16(DECLP)
#define LOADP(i) px##i = X[base + t + (i)*1024]; \
                 py##i = Y[base + t + (i)*1024]; \
                 pz##i = Z[base + t + (i)*1024]; \
                 dd##i = 1e10f;
  R16(LOADP)
  __shared__ float rv[16]; __shared__ int ri[16];
  __shared__ float scx, scy, scz;
  float cx = X[base], cy = Y[base], cz = Z[base];
  int cur = 0;
  for (int it=0; it<SP; it++){
    if (t == 0){
      const long bs = (long)b*SP + it;
      nxyz[bs*3+0] = cx; nxyz[bs*3+1] = cy; nxyz[bs*3+2] = cz;
      sto(dout, bs*3+0, cx, isb);
      sto(dout, bs*3+1, cy, isb);
      sto(dout, bs*3+2, cz, isb);
      sto(dout, OFF_IND + bs, (float)cur, isb);
    }
    float bv = -1.f; int bi = 0;
#define UPD(i) { float dx = px##i - cx, dy = py##i - cy, dz = pz##i - cz; \
                 float d2 = dx*dx + dy*dy; d2 = d2 + dz*dz; \
                 float dn = fminf(dd##i, d2); dd##i = dn; \
                 if (dn > bv){ bv = dn; bi = t + (i)*1024; } }
    R16(UPD)
    #pragma unroll
    for (int off=32; off; off>>=1){
      float ov = __shfl_down(bv, off, 64);
      int   oi = __shfl_down(bi, off, 64);
      if (ov > bv || (ov == bv && oi < bi)){ bv = ov; bi = oi; }
    }
    if ((t & 63) == 0){ rv[t>>6] = bv; ri[t>>6] = bi; }
    __syncthreads();
    // redundant block scan on ALL threads (identical result, no extra barrier)
    float gv = rv[0]; int gi = ri[0];
    #pragma unroll
    for (int w=1; w<16; w++){
      float vv = rv[w]; int ix = ri[w];
      if (vv > gv || (vv == gv && ix < gi)){ gv = vv; gi = ix; }
    }
    if (t == (gi & 1023)){
      float wx = 0.f, wy = 0.f, wz = 0.f;
      switch (gi >> 10){
#define CASEP(i) case i: wx = px##i; wy = py##i; wz = pz##i; break;
        R16(CASEP)
      }
      scx = wx; scy = wy; scz = wz;
    }
    __syncthreads();
    cur = gi; cx = scx; cy = scy; cz = scz;
  }
}

// ---------- 2. ball query (SoA f32) ----------
__global__ __launch_bounds__(256) void ballq_k(const float* __restrict__ X,
    const float* __restrict__ Y, const float* __restrict__ Z,
    const float* __restrict__ nxyz, int* __restrict__ bidx){
  #pragma clang fp contract(off)
  const int gw = (blockIdx.x*256 + threadIdx.x) >> 6;
  const int lane = threadIdx.x & 63;
  const int b = gw >> 8, base = b*NPT;
  const float cx = nxyz[gw*3+0], cy = nxyz[gw*3+1], cz = nxyz[gw*3+2];
  int cnt = 0, first = 0; bool havef = false;
  for (int st = 0; st < NPT && cnt < KS; st += 64){
    const int id = st + lane;
    float dx = X[base+id]-cx, dy = Y[base+id]-cy, dz = Z[base+id]-cz;
    float d2 = dx*dx + dy*dy; d2 = d2 + dz*dz;
    unsigned long long mk = __ballot(d2 <= 0.09f);
    if (mk){
      if (!havef){ first = st + __builtin_ctzll(mk); havef = true; }
      int rank = cnt + __popcll(mk & ((1ull<<lane)-1ull));
      if (((mk>>lane)&1ull) && rank < KS) bidx[gw*KS + rank] = id;
      cnt += __popcll(mk);
    }
  }
  if (cnt < KS && lane >= cnt && lane < KS) bidx[gw*KS + lane] = first;
}

// ---------- 3. gather -> h0 [n][296] bf16 via LDS tile ----------
__global__ __launch_bounds__(256) void gather_k(const void* __restrict__ xyz,
    const void* __restrict__ feat, const int* __restrict__ flag,
    const int* __restrict__ bidx, const float* __restrict__ nxyz,
    __hip_bfloat16* __restrict__ h0){
  __shared__ __hip_bfloat16 tile[64*296];
  const int isb = *flag;
  const int t = threadIdx.x, n0 = blockIdx.x*64;
  const int nl = t >> 2, cg = t & 3;
  const int n = n0 + nl, b = n >> 12, s = n >> 4;
  const int id = bidx[n];
  for (int j=0; j<74; j++){
    int c = cg*74 + j;
    float vv = 0.f;
    if (c < 3)       vv = (ldf(xyz, ((long)b*NPT + id)*3 + c, isb) - nxyz[(long)s*3 + c]) / 0.3f;
    else if (c < 291) vv = ldf(feat, ((long)b*CH + (c-3))*(long)NPT + id, isb);
    tile[nl*296 + c] = __float2bfloat16(vv);
  }
  __syncthreads();
  const uint4* src = (const uint4*)tile;
  uint4* dst = (uint4*)((char*)h0 + (long)n0*592);
  for (int j = t; j < 2368; j += 256) dst[j] = src[j];
}

// ---------- 4. MFMA GEMM: Out[n][o] = relu(BN(sum_k A[n][k]*W[o][k])) ----------
__global__ __launch_bounds__(256, 2) void gemm_k(
    const __hip_bfloat16* __restrict__ A, int astr,
    const __hip_bfloat16* __restrict__ W,
    const float* __restrict__ scale, const float* __restrict__ shift,
    __hip_bfloat16* __restrict__ Out, int ostr,
    int ktiles, int kvalid){
  extern __shared__ char lds[];
  const int t = threadIdx.x, lane = t & 63, wid = t >> 6;
  const int wm = wid & 1, wo = wid >> 1;
  const int bx = blockIdx.x, by = blockIdx.y;
  {
    const char* src = (const char*)(A + (long)bx*128*astr);
    const int chunks = (128*astr*2) >> 10;
    for (int c = wid; c < chunks; c += 4)
      gload_lds(src + c*1024 + lane*16, lds + c*1024);
  }
  f32x4 acc[4][3];
  #pragma unroll
  for (int mf=0; mf<4; mf++)
    #pragma unroll
    for (int of=0; of<3; of++) acc[mf][of] = (f32x4){0.f,0.f,0.f,0.f};

  const int mrow  = wm*64 + (lane & 15);
  const int kg    = (lane >> 4) * 8;
  const int obase = by*96 + wo*48 + (lane & 15);
  __syncthreads();

  for (int kt = 0; kt < ktiles; kt++){
    const int k0 = kt*32 + kg;
    const bool z = (k0 >= kvalid);
    const int k0c = z ? 0 : k0;
    bf16x8 a[4], bf[3];
    #pragma unroll
    for (int mf=0; mf<4; mf++)
      a[mf] = *(const bf16x8*)(lds + ((long)(mrow + mf*16)*astr + k0c)*2);
    if (z){
      bf16x8 zz = {0,0,0,0,0,0,0,0};
      #pragma unroll
      for (int mf=0; mf<4; mf++) a[mf] = zz;
    }
    #pragma unroll
    for (int of=0; of<3; of++)
      bf[of] = *(const bf16x8*)(W + (long)(obase + of*16)*296 + k0c);
    #pragma unroll
    for (int mf=0; mf<4; mf++)
      #pragma unroll
      for (int of=0; of<3; of++)
        acc[mf][of] = __builtin_amdgcn_mfma_f32_16x16x32_bf16(a[mf], bf[of], acc[mf][of], 0, 0, 0);
  }

  float sc[3], sh[3];
  #pragma unroll
  for (int of=0; of<3; of++){ sc[of] = scale[obase + of*16]; sh[of] = shift[obase + of*16]; }
  #pragma unroll
  for (int mf=0; mf<4; mf++)
    #pragma unroll
    for (int of=0; of<3; of++)
      #pragma unroll
      for (int r=0; r<4; r++){
        const long row = (long)bx*128 + wm*64 + mf*16 + (lane>>4)*4 + r;
        const int o = obase + of*16;
        float vv = acc[mf][of][r]*sc[of] + sh[of];
        Out[row*ostr + o] = __float2bfloat16(fmaxf(vv, 0.f));
      }
}

// ---------- 5. maxpool over k: h[n][288] -> out[b][o][s] ----------
__global__ __launch_bounds__(256) void maxk_k(const __hip_bfloat16* __restrict__ h,
    const int* __restrict__ flag, void* __restrict__ dout){
  __shared__ __hip_bfloat16 tile[128*288];
  const int isb = *flag;
  const int t = threadIdx.x;
  const int b = blockIdx.x >> 5, s0 = (blockIdx.x & 31)*8;
  const long n0 = (long)b*4096 + (long)s0*16;
  {
    const char* src = (const char*)(h + n0*288);
    for (int c = (t>>6); c < 72; c += 4)
      gload_lds(src + c*1024 + (t&63)*16, (char*)tile + c*1024);
  }
  __syncthreads();
  for (int o = t; o < 288; o += 256){
    float mx[8];
    #pragma unroll
    for (int sl=0; sl<8; sl++){
      float m = -1e30f;
      #pragma unroll
      for (int kk=0; kk<16; kk++)
        m = fmaxf(m, __bfloat162float(tile[(sl*16 + kk)*288 + o]));
      mx[sl] = m;
    }
    const long e0 = OFF_FEAT + (long)b*73728 + (long)o*256 + s0;
    if (isb){
      unsigned short u[8];
      #pragma unroll
      for (int sl=0; sl<8; sl++){
        __hip_bfloat16 hb = __float2bfloat16(mx[sl]);
        __builtin_memcpy(&u[sl], &hb, 2);
      }
      uint4 pk; __builtin_memcpy(&pk, u, 16);
      *(uint4*)((__hip_bfloat16*)dout + e0) = pk;
    } else {
      float* fo = (float*)dout + e0;
      *(float4*)fo     = make_float4(mx[0],mx[1],mx[2],mx[3]);
      *(float4*)(fo+4) = make_float4(mx[4],mx[5],mx[6],mx[7]);
    }
  }
}

extern "C" void kernel_launch(void* const* d_in, const int* in_sizes, int n_in,
                              void* d_out, int out_size, void* d_ws, size_t ws_size,
                              hipStream_t stream){
  const void* xyz  = d_in[0];
  const void* feat = d_in[1];
  const void* W0 = d_in[2];  const void* g0 = d_in[3];  const void* b0 = d_in[4];
  const void* m0 = d_in[5];  const void* v0 = d_in[6];
  const void* W1 = d_in[7];  const void* g1 = d_in[8];  const void* b1 = d_in[9];
  const void* m1 = d_in[10]; const void* v1 = d_in[11];
  const void* W2 = d_in[12]; const void* g2 = d_in[13]; const void* b2 = d_in[14];
  const void* m2 = d_in[15]; const void* v2 = d_in[16];

  char* ws = (char*)d_ws;
  int*   flag  = (int*)ws;                                   // [0,64)
  float* sc0   = (float*)(ws + 64);
  float* sh0   = sc0 + 288;
  float* sc1   = sc0 + 576;  float* sh1 = sc0 + 864;
  float* sc2   = sc0 + 1152; float* sh2 = sc0 + 1440;
  __hip_bfloat16* Wb0 = (__hip_bfloat16*)(ws + 7040);
  __hip_bfloat16* Wb1 = Wb0 + 288*296;
  __hip_bfloat16* Wb2 = Wb1 + 288*296;
  float* nxyz = (float*)(ws + 518656);
  int*   bidx = (int*)(ws + 567808);
  float* X    = (float*)(ws + 1048576);     // overlaid with bufA (dead after gather starts)
  float* Y    = X + NBAT*NPT;
  float* Z    = Y + NBAT*NPT;
  __hip_bfloat16* bufA = (__hip_bfloat16*)(ws + 1048576);
  __hip_bfloat16* bufB = (__hip_bfloat16*)(ws + 1048576 + 38797312);

  detect_k<<<1, 256, 0, stream>>>(xyz, flag);
  cvtxyz_k<<<3072, 256, 0, stream>>>(xyz, flag, X, Y, Z);
  cvtw_k<<<333, 256, 0, stream>>>(W0, g0, b0, m0, v0, flag, Wb0, sc0, sh0, 291);
  cvtw_k<<<333, 256, 0, stream>>>(W1, g1, b1, m1, v1, flag, Wb1, sc1, sh1, 288);
  cvtw_k<<<333, 256, 0, stream>>>(W2, g2, b2, m2, v2, flag, Wb2, sc2, sh2, 288);
  fps_k<<<NBAT, 1024, 0, stream>>>(X, Y, Z, flag, nxyz, d_out);
  ballq_k<<<1024, 256, 0, stream>>>(X, Y, Z, nxyz, bidx);
  gather_k<<<1024, 256, 0, stream>>>(xyz, feat, flag, bidx, nxyz, bufA);
  gemm_k<<<dim3(512,3), 256, 128*296*2, stream>>>(bufA, 296, Wb0, sc0, sh0, bufB, 288, 10, 296);
  gemm_k<<<dim3(512,3), 256, 128*288*2, stream>>>(bufB, 288, Wb1, sc1, sh1, bufA, 296, 9, 288);
  gemm_k<<<dim3(512,3), 256, 128*296*2, stream>>>(bufA, 296, Wb2, sc2, sh2, bufB, 288, 9, 288);
  maxk_k<<<512, 256, 0, stream>>>(bufB, flag, d_out);
}

// Round 4
// 1329.865 us; speedup vs baseline: 1.0355x; 1.0355x over previous
//
#include <hip/hip_runtime.h>
#include <hip/hip_bf16.h>
#include <string.h>

#define NPT   16384
#define NBAT  16
#define CH    288
#define SP    256
#define KS    16
#define OFF_FEAT 12288L
#define OFF_IND  1191936L

#define R16(M) M(0) M(1) M(2) M(3) M(4) M(5) M(6) M(7) M(8) M(9) M(10) M(11) M(12) M(13) M(14) M(15)

// ---------- helpers ----------
__device__ __forceinline__ float bfbits(unsigned short u){
  unsigned int x = ((unsigned int)u) << 16; float f; __builtin_memcpy(&f,&x,4); return f;
}
__device__ __forceinline__ float asf(unsigned int x){ float f; __builtin_memcpy(&f,&x,4); return f; }
__device__ __forceinline__ unsigned int asu(float f){ unsigned int x; __builtin_memcpy(&x,&f,4); return x; }
__device__ __forceinline__ float ldf(const void* p, long i, int isb){
  if (isb) return __bfloat162float(((const __hip_bfloat16*)p)[i]);
  return ((const float*)p)[i];
}
__device__ __forceinline__ void sto(void* p, long i, float v, int isb){
  if (isb) ((__hip_bfloat16*)p)[i] = __float2bfloat16(v);
  else     ((float*)p)[i] = v;
}
__device__ __forceinline__ void gload_lds(const void* g, void* l){
  __builtin_amdgcn_global_load_lds((const __attribute__((address_space(1))) void*)g,
      (__attribute__((address_space(3))) void*)l, 16, 0, 0);
}

typedef __attribute__((ext_vector_type(8))) short bf16x8;
typedef __attribute__((ext_vector_type(4))) float f32x4;

// ---------- 0. input dtype detection ----------
__global__ void detect_k(const void* __restrict__ xyz, int* __restrict__ flag){
  __shared__ float red[256];
  const int t = threadIdx.x;
  const unsigned short* u = (const unsigned short*)xyz;
  float m = 0.f;
  for (int i = t; i < 4096; i += 256){
    float f = fabsf(bfbits(u[i]));
    if (f != f) f = 1e30f;
    m = fmaxf(m, f);
  }
  red[t] = m; __syncthreads();
  for (int s = 128; s; s >>= 1){ if (t < s) red[t] = fmaxf(red[t], red[t+s]); __syncthreads(); }
  if (t == 0) *flag = (red[0] < 2.0f) ? 1 : 0;
}

// ---------- 0b. xyz -> f32 SoA ----------
__global__ __launch_bounds__(256) void cvtxyz_k(const void* __restrict__ xyz,
    const int* __restrict__ flag, float* __restrict__ X, float* __restrict__ Y,
    float* __restrict__ Z){
  const int e = blockIdx.x*256 + threadIdx.x;       // < 786432
  const int isb = *flag;
  float v = ldf(xyz, e, isb);
  int b = e / (NPT*3), r = e - b*(NPT*3), i = r/3, c = r - i*3;
  float* P = (c==0) ? X : ((c==1) ? Y : Z);
  P[b*NPT + i] = v;
}

// ---------- 0b'. pack points to (x|y<<16, z) bf16-raw pairs ----------
__global__ __launch_bounds__(256) void packpts_k(const float* __restrict__ X,
    const float* __restrict__ Y, const float* __restrict__ Z, uint2* __restrict__ P){
  const int e = blockIdx.x*256 + threadIdx.x;       // < 262144
  unsigned int xr = asu(X[e]) >> 16;
  unsigned int yr = asu(Y[e]) & 0xffff0000u;
  P[e] = make_uint2(xr | yr, asu(Z[e]));
}

// ---------- 0c. W -> bf16 [288][296] + BN scale/shift ----------
__global__ __launch_bounds__(256) void cvtw_k(const void* __restrict__ W,
    const void* __restrict__ g, const void* __restrict__ bb,
    const void* __restrict__ m, const void* __restrict__ v,
    const int* __restrict__ flag, __hip_bfloat16* __restrict__ Wbf,
    float* __restrict__ scale, float* __restrict__ shift, int Kin){
  const int isb = *flag;
  const int idx = blockIdx.x*256 + threadIdx.x;
  if (idx < 288*296){
    int o = idx / 296, k = idx - o*296;
    float val = (k < Kin) ? ldf(W, (long)o*Kin + k, isb) : 0.f;
    Wbf[idx] = __float2bfloat16(val);
  }
  if (idx < 288){
    float sc = ldf(g, idx, isb) * rsqrtf(ldf(v, idx, isb) + 1e-5f);
    scale[idx] = sc;
    shift[idx] = ldf(bb, idx, isb) - ldf(m, idx, isb)*sc;
  }
}

// ---------- 1. FPS (bf16 inputs): points LDS-resident ----------
// Rounds 2-3 showed the allocator pins ~64 VGPR (8 waves/EU) and spills any
// larger per-thread state. So: 128 KiB packed points in LDS (guaranteed
// residency), only dist[16] in registers (~40 VGPR). Exact numpy f32 math.
__global__ __launch_bounds__(1024, 4) void fps_bf16_k(const uint2* __restrict__ P,
    const int* __restrict__ flag, float* __restrict__ nxyz, void* __restrict__ dout){
  #pragma clang fp contract(off)
  if (*flag == 0) return;
  __shared__ uint2 pts[NPT];           // 131072 B
  __shared__ float rv[16]; __shared__ int ri[16];
  const int b = blockIdx.x, t = threadIdx.x;
  const int lane = t & 63, wid = t >> 6;
  {
    const char* src = (const char*)(P + b*NPT);
    for (int c = wid; c < 128; c += 16)
      gload_lds(src + c*1024 + lane*16, (char*)pts + c*1024);
  }
#define DECLD(i) float dd##i = 1e10f;
  R16(DECLD)
  __syncthreads();
  uint2 w0 = pts[0];
  float cx = asf(w0.x << 16), cy = asf(w0.x & 0xffff0000u), cz = asf(w0.y);
  int cur = 0;
  for (int it=0; it<SP; it++){
    if (t == 0){
      const long bs = (long)b*SP + it;
      nxyz[bs*3+0] = cx; nxyz[bs*3+1] = cy; nxyz[bs*3+2] = cz;
      sto(dout, bs*3+0, cx, 1);
      sto(dout, bs*3+1, cy, 1);
      sto(dout, bs*3+2, cz, 1);
      sto(dout, OFF_IND + bs, (float)cur, 1);
    }
    float bv = -1.f; int bi = 0;
#define UPD(i) { uint2 pw = pts[t + (i)*1024]; \
                 float x = asf(pw.x << 16), y = asf(pw.x & 0xffff0000u), z = asf(pw.y); \
                 float dx = x - cx, dy = y - cy, dz = z - cz; \
                 float d2 = dx*dx + dy*dy; d2 = d2 + dz*dz; \
                 float dn = fminf(dd##i, d2); dd##i = dn; \
                 if (dn > bv){ bv = dn; bi = t + (i)*1024; } }
    R16(UPD)
    #pragma unroll
    for (int off=32; off; off>>=1){
      float ov = __shfl_down(bv, off, 64);
      int   oi = __shfl_down(bi, off, 64);
      if (ov > bv || (ov == bv && oi < bi)){ bv = ov; bi = oi; }
    }
    if (lane == 0){ rv[wid] = bv; ri[wid] = bi; }
    __syncthreads();
    float gv = rv[0]; int gi = ri[0];
    #pragma unroll
    for (int w=1; w<16; w++){
      float vv = rv[w]; int ix = ri[w];
      if (vv > gv || (vv == gv && ix < gi)){ gv = vv; gi = ix; }
    }
    uint2 pw = pts[gi];                       // broadcast read
    cx = asf(pw.x << 16); cy = asf(pw.x & 0xffff0000u); cz = asf(pw.y);
    cur = gi;
    __syncthreads();                          // protect rv/ri reuse
  }
}

// ---------- 1'. FPS fallback (f32 inputs) ----------
__global__ __launch_bounds__(1024, 4) void fps_f32_k(const float* __restrict__ X,
    const float* __restrict__ Y, const float* __restrict__ Z,
    const int* __restrict__ flag, float* __restrict__ nxyz, void* __restrict__ dout){
  #pragma clang fp contract(off)
  if (*flag == 1) return;
  const int b = blockIdx.x, t = threadIdx.x;
  const int base = b*NPT;
#define DECLP(i) float px##i, py##i, pz##i, de##i;
  R16(DECLP)
#define LOADP(i) px##i = X[base + t + (i)*1024]; \
                 py##i = Y[base + t + (i)*1024]; \
                 pz##i = Z[base + t + (i)*1024]; \
                 de##i = 1e10f;
  R16(LOADP)
  __shared__ float rv[16]; __shared__ int ri[16];
  __shared__ float scx, scy, scz;
  float cx = X[base], cy = Y[base], cz = Z[base];
  int cur = 0;
  for (int it=0; it<SP; it++){
    if (t == 0){
      const long bs = (long)b*SP + it;
      nxyz[bs*3+0] = cx; nxyz[bs*3+1] = cy; nxyz[bs*3+2] = cz;
      sto(dout, bs*3+0, cx, 0);
      sto(dout, bs*3+1, cy, 0);
      sto(dout, bs*3+2, cz, 0);
      sto(dout, OFF_IND + bs, (float)cur, 0);
    }
    float bv = -1.f; int bi = 0;
#define UPD2(i) { float dx = px##i - cx, dy = py##i - cy, dz = pz##i - cz; \
                 float d2 = dx*dx + dy*dy; d2 = d2 + dz*dz; \
                 float dn = fminf(de##i, d2); de##i = dn; \
                 if (dn > bv){ bv = dn; bi = t + (i)*1024; } }
    R16(UPD2)
    #pragma unroll
    for (int off=32; off; off>>=1){
      float ov = __shfl_down(bv, off, 64);
      int   oi = __shfl_down(bi, off, 64);
      if (ov > bv || (ov == bv && oi < bi)){ bv = ov; bi = oi; }
    }
    if ((t & 63) == 0){ rv[t>>6] = bv; ri[t>>6] = bi; }
    __syncthreads();
    float gv = rv[0]; int gi = ri[0];
    #pragma unroll
    for (int w=1; w<16; w++){
      float vv = rv[w]; int ix = ri[w];
      if (vv > gv || (vv == gv && ix < gi)){ gv = vv; gi = ix; }
    }
    if (t == (gi & 1023)){
      float wx = 0.f, wy = 0.f, wz = 0.f;
      switch (gi >> 10){
#define CASEP(i) case i: wx = px##i; wy = py##i; wz = pz##i; break;
        R16(CASEP)
      }
      scx = wx; scy = wy; scz = wz;
    }
    __syncthreads();
    cur = gi; cx = scx; cy = scy; cz = scz;
  }
}

// ---------- 2. ball query (SoA f32) ----------
__global__ __launch_bounds__(256) void ballq_k(const float* __restrict__ X,
    const float* __restrict__ Y, const float* __restrict__ Z,
    const float* __restrict__ nxyz, int* __restrict__ bidx){
  #pragma clang fp contract(off)
  const int gw = (blockIdx.x*256 + threadIdx.x) >> 6;
  const int lane = threadIdx.x & 63;
  const int b = gw >> 8, base = b*NPT;
  const float cx = nxyz[gw*3+0], cy = nxyz[gw*3+1], cz = nxyz[gw*3+2];
  int cnt = 0, first = 0; bool havef = false;
  for (int st = 0; st < NPT && cnt < KS; st += 64){
    const int id = st + lane;
    float dx = X[base+id]-cx, dy = Y[base+id]-cy, dz = Z[base+id]-cz;
    float d2 = dx*dx + dy*dy; d2 = d2 + dz*dz;
    unsigned long long mk = __ballot(d2 <= 0.09f);
    if (mk){
      if (!havef){ first = st + __builtin_ctzll(mk); havef = true; }
      int rank = cnt + __popcll(mk & ((1ull<<lane)-1ull));
      if (((mk>>lane)&1ull) && rank < KS) bidx[gw*KS + rank] = id;
      cnt += __popcll(mk);
    }
  }
  if (cnt < KS && lane >= cnt && lane < KS) bidx[gw*KS + lane] = first;
}

// ---------- 3. gather -> h0 [n][296] bf16 via LDS tile ----------
__global__ __launch_bounds__(256) void gather_k(const void* __restrict__ xyz,
    const void* __restrict__ feat, const int* __restrict__ flag,
    const int* __restrict__ bidx, const float* __restrict__ nxyz,
    __hip_bfloat16* __restrict__ h0){
  __shared__ __hip_bfloat16 tile[64*296];
  const int isb = *flag;
  const int t = threadIdx.x, n0 = blockIdx.x*64;
  const int nl = t >> 2, cg = t & 3;
  const int n = n0 + nl, b = n >> 12, s = n >> 4;
  const int id = bidx[n];
  for (int j=0; j<74; j++){
    int c = cg*74 + j;
    float vv = 0.f;
    if (c < 3)       vv = (ldf(xyz, ((long)b*NPT + id)*3 + c, isb) - nxyz[(long)s*3 + c]) / 0.3f;
    else if (c < 291) vv = ldf(feat, ((long)b*CH + (c-3))*(long)NPT + id, isb);
    tile[nl*296 + c] = __float2bfloat16(vv);
  }
  __syncthreads();
  const uint4* src = (const uint4*)tile;
  uint4* dst = (uint4*)((char*)h0 + (long)n0*592);
  for (int j = t; j < 2368; j += 256) dst[j] = src[j];
}

// ---------- 4. MFMA GEMM: Out[n][o] = relu(BN(sum_k A[n][k]*W[o][k])) ----------
__global__ __launch_bounds__(256, 2) void gemm_k(
    const __hip_bfloat16* __restrict__ A, int astr,
    const __hip_bfloat16* __restrict__ W,
    const float* __restrict__ scale, const float* __restrict__ shift,
    __hip_bfloat16* __restrict__ Out, int ostr,
    int ktiles, int kvalid){
  extern __shared__ char lds[];
  const int t = threadIdx.x, lane = t & 63, wid = t >> 6;
  const int wm = wid & 1, wo = wid >> 1;
  const int bx = blockIdx.x, by = blockIdx.y;
  {
    const char* src = (const char*)(A + (long)bx*128*astr);
    const int chunks = (128*astr*2) >> 10;
    for (int c = wid; c < chunks; c += 4)
      gload_lds(src + c*1024 + lane*16, lds + c*1024);
  }
  f32x4 acc[4][3];
  #pragma unroll
  for (int mf=0; mf<4; mf++)
    #pragma unroll
    for (int of=0; of<3; of++) acc[mf][of] = (f32x4){0.f,0.f,0.f,0.f};

  const int mrow  = wm*64 + (lane & 15);
  const int kg    = (lane >> 4) * 8;
  const int obase = by*96 + wo*48 + (lane & 15);
  __syncthreads();

  for (int kt = 0; kt < ktiles; kt++){
    const int k0 = kt*32 + kg;
    const bool z = (k0 >= kvalid);
    const int k0c = z ? 0 : k0;
    bf16x8 a[4], bf[3];
    #pragma unroll
    for (int mf=0; mf<4; mf++)
      a[mf] = *(const bf16x8*)(lds + ((long)(mrow + mf*16)*astr + k0c)*2);
    if (z){
      bf16x8 zz = {0,0,0,0,0,0,0,0};
      #pragma unroll
      for (int mf=0; mf<4; mf++) a[mf] = zz;
    }
    #pragma unroll
    for (int of=0; of<3; of++)
      bf[of] = *(const bf16x8*)(W + (long)(obase + of*16)*296 + k0c);
    #pragma unroll
    for (int mf=0; mf<4; mf++)
      #pragma unroll
      for (int of=0; of<3; of++)
        acc[mf][of] = __builtin_amdgcn_mfma_f32_16x16x32_bf16(a[mf], bf[of], acc[mf][of], 0, 0, 0);
  }

  float sc[3], sh[3];
  #pragma unroll
  for (int of=0; of<3; of++){ sc[of] = scale[obase + of*16]; sh[of] = shift[obase + of*16]; }
  #pragma unroll
  for (int mf=0; mf<4; mf++)
    #pragma unroll
    for (int of=0; of<3; of++)
      #pragma unroll
      for (int r=0; r<4; r++){
        const long row = (long)bx*128 + wm*64 + mf*16 + (lane>>4)*4 + r;
        const int o = obase + of*16;
        float vv = acc[mf][of][r]*sc[of] + sh[of];
        Out[row*ostr + o] = __float2bfloat16(fmaxf(vv, 0.f));
      }
}

// ---------- 5. maxpool over k: h[n][288] -> out[b][o][s] ----------
__global__ __launch_bounds__(256) void maxk_k(const __hip_bfloat16* __restrict__ h,
    const int* __restrict__ flag, void* __restrict__ dout){
  __shared__ __hip_bfloat16 tile[128*288];
  const int isb = *flag;
  const int t = threadIdx.x;
  const int b = blockIdx.x >> 5, s0 = (blockIdx.x & 31)*8;
  const long n0 = (long)b*4096 + (long)s0*16;
  {
    const char* src = (const char*)(h + n0*288);
    for (int c = (t>>6); c < 72; c += 4)
      gload_lds(src + c*1024 + (t&63)*16, (char*)tile + c*1024);
  }
  __syncthreads();
  for (int o = t; o < 288; o += 256){
    float mx[8];
    #pragma unroll
    for (int sl=0; sl<8; sl++){
      float m = -1e30f;
      #pragma unroll
      for (int kk=0; kk<16; kk++)
        m = fmaxf(m, __bfloat162float(tile[(sl*16 + kk)*288 + o]));
      mx[sl] = m;
    }
    const long e0 = OFF_FEAT + (long)b*73728 + (long)o*256 + s0;
    if (isb){
      unsigned short u[8];
      #pragma unroll
      for (int sl=0; sl<8; sl++){
        __hip_bfloat16 hb = __float2bfloat16(mx[sl]);
        __builtin_memcpy(&u[sl], &hb, 2);
      }
      uint4 pk; __builtin_memcpy(&pk, u, 16);
      *(uint4*)((__hip_bfloat16*)dout + e0) = pk;
    } else {
      float* fo = (float*)dout + e0;
      *(float4*)fo     = make_float4(mx[0],mx[1],mx[2],mx[3]);
      *(float4*)(fo+4) = make_float4(mx[4],mx[5],mx[6],mx[7]);
    }
  }
}

extern "C" void kernel_launch(void* const* d_in, const int* in_sizes, int n_in,
                              void* d_out, int out_size, void* d_ws, size_t ws_size,
                              hipStream_t stream){
  const void* xyz  = d_in[0];
  const void* feat = d_in[1];
  const void* W0 = d_in[2];  const void* g0 = d_in[3];  const void* b0 = d_in[4];
  const void* m0 = d_in[5];  const void* v0 = d_in[6];
  const void* W1 = d_in[7];  const void* g1 = d_in[8];  const void* b1 = d_in[9];
  const void* m1 = d_in[10]; const void* v1 = d_in[11];
  const void* W2 = d_in[12]; const void* g2 = d_in[13]; const void* b2 = d_in[14];
  const void* m2 = d_in[15]; const void* v2 = d_in[16];

  char* ws = (char*)d_ws;
  int*   flag  = (int*)ws;                                   // [0,64)
  float* sc0   = (float*)(ws + 64);
  float* sh0   = sc0 + 288;
  float* sc1   = sc0 + 576;  float* sh1 = sc0 + 864;
  float* sc2   = sc0 + 1152; float* sh2 = sc0 + 1440;
  __hip_bfloat16* Wb0 = (__hip_bfloat16*)(ws + 7040);
  __hip_bfloat16* Wb1 = Wb0 + 288*296;
  __hip_bfloat16* Wb2 = Wb1 + 288*296;
  float* nxyz = (float*)(ws + 518656);
  int*   bidx = (int*)(ws + 567808);
  // X/Y/Z/P live inside the bufA region (dead before gather writes bufA)
  float* X    = (float*)(ws + 1048576);
  float* Y    = (float*)(ws + 2097152);
  float* Z    = (float*)(ws + 3145728);
  uint2* P    = (uint2*)(ws + 4194304);                      // 2 MB
  __hip_bfloat16* bufA = (__hip_bfloat16*)(ws + 1048576);
  __hip_bfloat16* bufB = (__hip_bfloat16*)(ws + 1048576 + 38797312);

  detect_k<<<1, 256, 0, stream>>>(xyz, flag);
  cvtxyz_k<<<3072, 256, 0, stream>>>(xyz, flag, X, Y, Z);
  packpts_k<<<1024, 256, 0, stream>>>(X, Y, Z, P);
  cvtw_k<<<333, 256, 0, stream>>>(W0, g0, b0, m0, v0, flag, Wb0, sc0, sh0, 291);
  cvtw_k<<<333, 256, 0, stream>>>(W1, g1, b1, m1, v1, flag, Wb1, sc1, sh1, 288);
  cvtw_k<<<333, 256, 0, stream>>>(W2, g2, b2, m2, v2, flag, Wb2, sc2, sh2, 288);
  fps_bf16_k<<<NBAT, 1024, 0, stream>>>(P, flag, nxyz, d_out);
  fps_f32_k<<<NBAT, 1024, 0, stream>>>(X, Y, Z, flag, nxyz, d_out);
  ballq_k<<<1024, 256, 0, stream>>>(X, Y, Z, nxyz, bidx);
  gather_k<<<1024, 256, 0, stream>>>(xyz, feat, flag, bidx, nxyz, bufA);
  gemm_k<<<dim3(512,3), 256, 128*296*2, stream>>>(bufA, 296, Wb0, sc0, sh0, bufB, 288, 10, 296);
  gemm_k<<<dim3(512,3), 256, 128*288*2, stream>>>(bufB, 288, Wb1, sc1, sh1, bufA, 296, 9, 288);
  gemm_k<<<dim3(512,3), 256, 128*296*2, stream>>>(bufA, 296, Wb2, sc2, sh2, bufB, 288, 9, 288);
  maxk_k<<<512, 256, 0, stream>>>(bufB, flag, d_out);
}